// Round 1
// baseline (843.590 us; speedup 1.0000x reference)
//
#include <hip/hip_runtime.h>
#include <cstdint>
#include <cstddef>

// ---------------------------------------------------------------------------
// MultiHeadSelfAttention: x(64,64,4096) fp32; W q/k/v/o (4096,4096); quirky RoPE
// Pipeline: fused cast->f16 | GEMM qkv (M4096,N12288,K4096) | fused rope+attn
//           per (b,h) | GEMM out-proj -> fp32 d_out
// All MFMA f16 16x16x32, fp32 accumulate.
// R3: GEMMs rewritten to the 256x256 8-phase template (T2+T3+T4+T5):
//     - BK=64, 8 waves (2Mx4N), 512 thr, double-buffered 128 KiB LDS
//     - per-phase: ds_read quadrant | 1 half-tile global_load_lds | s_barrier |
//       lgkmcnt(0) | setprio(1) 16xMFMA setprio(0) | s_barrier
//     - counted s_waitcnt vmcnt(4) ONCE per K-tile (phase 4), never 0 in loop.
//       Staging order: A-halves of tile t+1 at phases 1-2 (other buffer),
//       B-halves of tile t+2 at phases 3-4 (current buffer, B region is done
//       being read after phase 2) -> vmcnt(4)@p4 forces exactly what tile t+1
//       phase 1 needs; 2 half-tiles stay in flight across every barrier.
//     - LDS XOR swizzle phys_chunk = chunk ^ (row&7): applied on the
//       pre-swizzled GLOBAL source (global_load_lds writes linearly) and on
//       the ds_read address (fragment rows == fr mod 8 -> per-lane constant).
//     - XCD-bijective blockIdx swizzle (grid % 8 == 0 for both GEMMs).
// ---------------------------------------------------------------------------

typedef _Float16 half8 __attribute__((ext_vector_type(8)));
typedef float floatx4 __attribute__((ext_vector_type(4)));

#define NELT_W 16777216u   // 4096*4096
#define NEG_LOG2_10000_OVER_2048 (-0.0064881408103278559f)

// async global->LDS, 16 bytes per lane
__device__ __forceinline__ void gl_lds16(const void* g, void* l) {
    __builtin_amdgcn_global_load_lds(
        (const __attribute__((address_space(1))) void*)(void*)g,
        (__attribute__((address_space(3))) void*)l,
        16, 0, 0);
}

// ---------------------------------------------------------------------------
// fused fp32 -> f16 cast of all 5 tensors: blockIdx.y selects tensor
// ---------------------------------------------------------------------------
__global__ __launch_bounds__(256) void cast5_kernel(
    const float* __restrict__ x,  const float* __restrict__ wq,
    const float* __restrict__ wk, const float* __restrict__ wv,
    const float* __restrict__ wo,
    _Float16* __restrict__ xh, _Float16* __restrict__ wcat,
    _Float16* __restrict__ woh)
{
    const float* s;
    _Float16* d;
    switch (blockIdx.y) {
        case 0:  s = x;  d = xh;                 break;
        case 1:  s = wq; d = wcat;               break;
        case 2:  s = wk; d = wcat + NELT_W;      break;
        case 3:  s = wv; d = wcat + 2 * NELT_W;  break;
        default: s = wo; d = woh;                break;
    }
    int i0 = (blockIdx.x * 256 + threadIdx.x) * 8;
    int stride = gridDim.x * 256 * 8;
    for (int i = i0; i < (int)NELT_W; i += stride) {
        const float4 a = *(const float4*)(s + i);
        const float4 b = *(const float4*)(s + i + 4);
        half8 h;
        h[0] = (_Float16)a.x; h[1] = (_Float16)a.y;
        h[2] = (_Float16)a.z; h[3] = (_Float16)a.w;
        h[4] = (_Float16)b.x; h[5] = (_Float16)b.y;
        h[6] = (_Float16)b.z; h[7] = (_Float16)b.w;
        *(half8*)(d + i) = h;
    }
}

__global__ __launch_bounds__(256) void biascat_kernel(
    const float* __restrict__ bq, const float* __restrict__ bk,
    const float* __restrict__ bv, float* __restrict__ out)
{
    int i = blockIdx.x * 256 + threadIdx.x;
    if (i < 4096) {
        out[i]        = bq[i];
        out[4096 + i] = bk[i];
        out[8192 + i] = bv[i];
    }
}

// ---------------------------------------------------------------------------
// NT GEMM, 256x256 tile, BK=64, 8-phase schedule.
// C[m,n] = sum_k A[m,k]*B[n,k] + bias[n]; A: MxK f16 rm, B: NxK f16 rm.
// Requires M%256==0, N%256==0, K%128==0, grid%8==0.
// ---------------------------------------------------------------------------

// stage one 64-row chunk pair (one half-tile = 128 rows = 2 instrs)
#define STAGE(gb_, lb_, kt_, half_) do {                                      \
    const int R0_ = (half_) << 7;                                             \
    gl_lds16((gb_) + (size_t)R0_ * K + (kt_), (lb_) + R0_ * 64);              \
    gl_lds16((gb_) + (size_t)(R0_ + 64) * K + (kt_), (lb_) + (R0_ + 64) * 64);\
} while (0)

// load A fragments for quadrant qm: rows wm + qm*64 + mt*16 + fr
#define LDA(qm_) do {                                                         \
    const _Float16* pa_ = As + bufo + (size_t)(wm + (qm_) * 64 + fr) * 64;    \
    _Pragma("unroll") for (int mt_ = 0; mt_ < 4; ++mt_) {                     \
        af[mt_][0] = *(const half8*)(pa_ + mt_ * 1024 + sw0);                 \
        af[mt_][1] = *(const half8*)(pa_ + mt_ * 1024 + sw1);                 \
    }                                                                         \
} while (0)

// load B fragments for quadrant qn into dst: rows wn + qn*32 + nt*16 + fr
#define LDB(qn_, dst_) do {                                                   \
    const _Float16* pb_ = Bs + bufo + (size_t)(wn + (qn_) * 32 + fr) * 64;    \
    _Pragma("unroll") for (int nt_ = 0; nt_ < 2; ++nt_) {                     \
        dst_[nt_][0] = *(const half8*)(pb_ + nt_ * 1024 + sw0);               \
        dst_[nt_][1] = *(const half8*)(pb_ + nt_ * 1024 + sw1);               \
    }                                                                         \
} while (0)

// 16 MFMAs for quadrant (qm, qn)
#define MFMAQ(qm_, qn_, bq_) do {                                             \
    _Pragma("unroll") for (int s_ = 0; s_ < 2; ++s_)                          \
    _Pragma("unroll") for (int mt_ = 0; mt_ < 4; ++mt_)                       \
    _Pragma("unroll") for (int nt_ = 0; nt_ < 2; ++nt_)                       \
        acc[(qm_) * 4 + mt_][(qn_) * 2 + nt_] =                               \
            __builtin_amdgcn_mfma_f32_16x16x32_f16(                           \
                af[mt_][s_], bq_[nt_][s_],                                    \
                acc[(qm_) * 4 + mt_][(qn_) * 2 + nt_], 0, 0, 0);              \
} while (0)

#define PHASE_MID()                                                           \
    __builtin_amdgcn_s_barrier();                                             \
    asm volatile("s_waitcnt lgkmcnt(0)");                                     \
    __builtin_amdgcn_sched_barrier(0);                                        \
    __builtin_amdgcn_s_setprio(1)

#define PHASE_END()                                                           \
    __builtin_amdgcn_s_setprio(0);                                            \
    __builtin_amdgcn_s_barrier()

// one K-tile = 4 phases; uses scope vars t, bufo, nbufo
#define TILE() do {                                                           \
    const int ktn_ = (t + 1) << 6;                                            \
    const int kt2_ = (t + 2) << 6;                                            \
    const bool s1_ = (t + 1 < NT);                                            \
    const bool s2_ = (t + 2 < NT);                                            \
    /* phase 1: quadrant (0,0); stage A-half0 of t+1 -> other buffer */       \
    LDA(0); LDB(0, bq0);                                                      \
    if (s1_) STAGE(Ab, AsT + nbufo, ktn_, 0);                                 \
    PHASE_MID();                                                              \
    MFMAQ(0, 0, bq0);                                                         \
    PHASE_END();                                                              \
    /* phase 2: quadrant (0,1); stage A-half1 of t+1 */                       \
    LDB(1, bq1);                                                              \
    if (s1_) STAGE(Ab, AsT + nbufo, ktn_, 1);                                 \
    PHASE_MID();                                                              \
    MFMAQ(0, 1, bq1);                                                         \
    PHASE_END();                                                              \
    /* phase 3: quadrant (1,1); stage B-half0 of t+2 -> current buffer */     \
    LDA(1);                                                                   \
    if (s2_) STAGE(Bb, BsT + bufo, kt2_, 0);                                  \
    PHASE_MID();                                                              \
    MFMAQ(1, 1, bq1);                                                         \
    PHASE_END();                                                              \
    /* phase 4: quadrant (1,0); stage B-half1 of t+2; counted vmcnt */        \
    if (s2_) STAGE(Bb, BsT + bufo, kt2_, 1);                                  \
    if (t < NT - 2) asm volatile("s_waitcnt vmcnt(4)");                       \
    else            asm volatile("s_waitcnt vmcnt(0)");                       \
    __builtin_amdgcn_s_barrier();                                             \
    __builtin_amdgcn_sched_barrier(0);                                        \
    __builtin_amdgcn_s_setprio(1);                                            \
    MFMAQ(1, 0, bq0);                                                         \
    PHASE_END();                                                              \
} while (0)

template <int OUT_F16>
__global__ __launch_bounds__(512, 2) void gemm_nt_256(
    const _Float16* __restrict__ A, const _Float16* __restrict__ B,
    const float* __restrict__ bias, void* __restrict__ Cout,
    int M, int N, int K)
{
    __shared__ __align__(16) _Float16 As[2 * 256 * 64];   // 64 KiB
    __shared__ __align__(16) _Float16 Bs[2 * 256 * 64];   // 64 KiB

    const int tid = threadIdx.x;
    // XCD-bijective block swizzle (grid multiple of 8)
    const int nwg  = gridDim.x;
    const int swz  = (blockIdx.x & 7) * (nwg >> 3) + (blockIdx.x >> 3);
    const int gn   = N >> 8;
    const int row0 = (swz / gn) << 8;
    const int col0 = (swz % gn) << 8;

    const int wave = tid >> 6;
    const int lane = tid & 63;
    const int wm = (wave >> 2) << 7;    // 0 or 128
    const int wn = (wave & 3) << 6;     // 0,64,128,192

    // fragment read constants; frag row = (16-mult) + fr so row&7 == fr&7
    const int fr  = lane & 15;
    const int g4  = lane >> 4;
    const int sw0 = ((g4 ^ (fr & 7)) << 3);        // k-slice 0 chunk, swizzled
    const int sw1 = (((4 + g4) ^ (fr & 7)) << 3);  // k-slice 1 chunk, swizzled

    // staging: thread t -> row tid>>3, phys chunk tid&7; fetch logical chunk
    // (tid&7)^(row&7) so that ds_read-side swizzle finds the right data.
    const int srow = tid >> 3;
    const int scol = ((tid & 7) ^ (srow & 7)) << 3;
    const _Float16* Ab = A + (size_t)(row0 + srow) * K + scol;
    const _Float16* Bb = B + (size_t)(col0 + srow) * K + scol;
    _Float16* AsT = As + tid * 8;
    _Float16* BsT = Bs + tid * 8;

    floatx4 acc[8][4];
#pragma unroll
    for (int i = 0; i < 8; i++)
#pragma unroll
        for (int j = 0; j < 4; j++) acc[i][j] = (floatx4){0.f, 0.f, 0.f, 0.f};

    half8 af[4][2], bq0[2][2], bq1[2][2];

    const int NT = K >> 6;

    // prologue: B(0), A(0) -> buf0; B(1) -> buf1. Leave B(1) in flight.
    STAGE(Bb, BsT, 0, 0);
    STAGE(Bb, BsT, 0, 1);
    STAGE(Ab, AsT, 0, 0);
    STAGE(Ab, AsT, 0, 1);
    STAGE(Bb, BsT + 16384, 64, 0);
    STAGE(Bb, BsT + 16384, 64, 1);
    asm volatile("s_waitcnt vmcnt(4)");
    __builtin_amdgcn_s_barrier();

    for (int tt = 0; tt < NT; tt += 2) {
        { const int t = tt;     const int bufo = 0;     const int nbufo = 16384; TILE(); }
        { const int t = tt + 1; const int bufo = 16384; const int nbufo = 0;     TILE(); }
    }

    // epilogue: C/D layout col=lane&15, row=(lane>>4)*4+reg
    const int crow = row0 + wm + (g4 << 2);
    const int ccol = col0 + wn + fr;
#pragma unroll
    for (int mi = 0; mi < 8; mi++) {
#pragma unroll
        for (int ni = 0; ni < 4; ni++) {
            const int gc = ccol + ni * 16;
            const float bv = bias[gc];
#pragma unroll
            for (int r2 = 0; r2 < 4; r2++) {
                const int gr = crow + mi * 16 + r2;
                const float v = acc[mi][ni][r2] + bv;
                if (OUT_F16)
                    ((_Float16*)Cout)[(size_t)gr * N + gc] = (_Float16)v;
                else
                    ((float*)Cout)[(size_t)gr * N + gc] = v;
            }
        }
    }
    (void)M;
}

// ---------------------------------------------------------------------------
// Fused rope + attention. One block per (b,h). qkv: (4096, 12288) f16,
// q at col h*64+d, k at 4096+h*64+d, v at 8192+h*64+d. out: (4096,4096) f16.
// RoPE quirk: theta = b * 10000^(-(s*32 + d/2)/2048).
// ---------------------------------------------------------------------------
__global__ __launch_bounds__(256) void attn_kernel(
    const _Float16* __restrict__ qkv, _Float16* __restrict__ out)
{
    __shared__ __align__(16) _Float16 qs[64][72];
    __shared__ __align__(16) _Float16 ks[64][72];
    __shared__ __align__(16) _Float16 vt[64][72];   // vt[d][s_k]
    __shared__ __align__(16) _Float16 ps[4][16][72];

    const int tid  = threadIdx.x;
    const int bb   = blockIdx.x >> 6;   // batch
    const int hh   = blockIdx.x & 63;   // head
    const int wave = tid >> 6;
    const int lane = tid & 63;
    const int r  = tid >> 2;            // row s, 0..63
    const int cb = (tid & 3) * 8;       // col base within 32-chunk
    const float fb = (float)bb;

    const _Float16* grow = qkv + (size_t)(bb * 64 + r) * 12288 + hh * 64;

#pragma unroll
    for (int u = 0; u < 2; u++) {
        const int c8 = cb + u * 32;     // contiguous 32-col chunks per 4-lane group
        half8 q8 = *(const half8*)(grow + c8);
        half8 k8 = *(const half8*)(grow + 4096 + c8);
        half8 v8 = *(const half8*)(grow + 8192 + c8);
#pragma unroll
        for (int p = 0; p < 4; p++) {
            const int m = r * 32 + (c8 >> 1) + p;
            const float theta = fb * exp2f((float)m * NEG_LOG2_10000_OVER_2048);
            float sn, cs;
            __sincosf(theta, &sn, &cs);
            const float qe = (float)q8[2 * p], qo = (float)q8[2 * p + 1];
            q8[2 * p]     = (_Float16)(qe * cs - qo * sn);
            q8[2 * p + 1] = (_Float16)(qe * sn + qo * cs);
            const float ke = (float)k8[2 * p], ko = (float)k8[2 * p + 1];
            k8[2 * p]     = (_Float16)(ke * cs - ko * sn);
            k8[2 * p + 1] = (_Float16)(ke * sn + ko * cs);
        }
        *(half8*)&qs[r][c8] = q8;
        *(half8*)&ks[r][c8] = k8;
#pragma unroll
        for (int j = 0; j < 8; j++) vt[c8 + j][r] = v8[j];
    }
    __syncthreads();

    const int fr = lane & 15;
    const int fc = (lane >> 4) * 8;

    // scores: wave handles rows sq in [wave*16, wave*16+16), all 64 cols
    floatx4 sa[4];
#pragma unroll
    for (int t = 0; t < 4; t++) sa[t] = (floatx4){0.f, 0.f, 0.f, 0.f};
    half8 a0 = *(const half8*)&qs[wave * 16 + fr][fc];
    half8 a1 = *(const half8*)&qs[wave * 16 + fr][fc + 32];
#pragma unroll
    for (int t = 0; t < 4; t++) {
        half8 kb0 = *(const half8*)&ks[t * 16 + fr][fc];
        half8 kb1 = *(const half8*)&ks[t * 16 + fr][fc + 32];
        sa[t] = __builtin_amdgcn_mfma_f32_16x16x32_f16(a0, kb0, sa[t], 0, 0, 0);
        sa[t] = __builtin_amdgcn_mfma_f32_16x16x32_f16(a1, kb1, sa[t], 0, 0, 0);
    }

    // softmax over 64 cols; row = wave*16 + (lane>>4)*4 + i
#pragma unroll
    for (int i = 0; i < 4; i++) {
        float mx = -1e30f;
#pragma unroll
        for (int t = 0; t < 4; t++) mx = fmaxf(mx, sa[t][i]);
#pragma unroll
        for (int d = 1; d < 16; d <<= 1) mx = fmaxf(mx, __shfl_xor(mx, d));
        float sum = 0.f;
        float pv[4];
#pragma unroll
        for (int t = 0; t < 4; t++) {
            const float e = __expf((sa[t][i] - mx) * 0.125f);
            pv[t] = e;
            sum += e;
        }
#pragma unroll
        for (int d = 1; d < 16; d <<= 1) sum += __shfl_xor(sum, d);
        const float inv = 1.0f / sum;
        const int prow = ((lane >> 4) << 2) + i;
#pragma unroll
        for (int t = 0; t < 4; t++)
            ps[wave][prow][t * 16 + fr] = (_Float16)(pv[t] * inv);
    }
    // ps[wave] is written+read only by this wave; LDS ops are wave-ordered.

    // PV: O[sq][d] = sum_sk P[sq][sk] * V[sk][d]
    half8 pa0 = *(const half8*)&ps[wave][fr][fc];
    half8 pa1 = *(const half8*)&ps[wave][fr][fc + 32];
    floatx4 oa[4];
#pragma unroll
    for (int t = 0; t < 4; t++) oa[t] = (floatx4){0.f, 0.f, 0.f, 0.f};
#pragma unroll
    for (int t = 0; t < 4; t++) {
        half8 vb0 = *(const half8*)&vt[t * 16 + fr][fc];
        half8 vb1 = *(const half8*)&vt[t * 16 + fr][fc + 32];
        oa[t] = __builtin_amdgcn_mfma_f32_16x16x32_f16(pa0, vb0, oa[t], 0, 0, 0);
        oa[t] = __builtin_amdgcn_mfma_f32_16x16x32_f16(pa1, vb1, oa[t], 0, 0, 0);
    }

    _Float16* obase = out + (size_t)(bb * 64) * 4096 + hh * 64;
#pragma unroll
    for (int t = 0; t < 4; t++)
#pragma unroll
        for (int i = 0; i < 4; i++) {
            const int sq = wave * 16 + ((lane >> 4) << 2) + i;
            obase[(size_t)sq * 4096 + t * 16 + fr] = (_Float16)oa[t][i];
        }
}

// ---------------------------------------------------------------------------
// launcher
// ---------------------------------------------------------------------------
extern "C" void kernel_launch(void* const* d_in, const int* in_sizes, int n_in,
                              void* d_out, int out_size, void* d_ws, size_t ws_size,
                              hipStream_t stream)
{
    const float* x  = (const float*)d_in[0];
    const float* wq = (const float*)d_in[1];
    const float* bq = (const float*)d_in[2];
    const float* wk = (const float*)d_in[3];
    const float* bk = (const float*)d_in[4];
    const float* wv = (const float*)d_in[5];
    const float* bv = (const float*)d_in[6];
    const float* wo = (const float*)d_in[7];
    const float* bo = (const float*)d_in[8];

    char* ws = (char*)d_ws;
    _Float16* xh      = (_Float16*)(ws);                          // 32 MiB
    _Float16* wcat    = (_Float16*)(ws + 33554432);               // 96 MiB (wq|wk|wv)
    _Float16* woh     = (_Float16*)(ws + 134217728);              // 32 MiB
    _Float16* qkv     = (_Float16*)(ws + 167772160);              // 96 MiB
    _Float16* attnbuf = (_Float16*)(ws + 268435456);              // 32 MiB
    float*    biascat = (float*)(ws + 301989888);                 // 48 KiB

    cast5_kernel<<<dim3(1024, 5), dim3(256), 0, stream>>>(
        x, wq, wk, wv, wo, xh, wcat, woh);
    biascat_kernel<<<dim3(16), dim3(256), 0, stream>>>(bq, bk, bv, biascat);

    // QKV projection: C(4096,12288) = xh @ wcat^T + biascat
    gemm_nt_256<1><<<dim3(768), dim3(512), 0, stream>>>(
        xh, wcat, biascat, qkv, 4096, 12288, 4096);

    // fused rope + attention
    attn_kernel<<<dim3(4096), dim3(256), 0, stream>>>(qkv, attnbuf);

    // output projection: d_out(4096,4096) fp32 = attn @ wo^T + bo
    gemm_nt_256<0><<<dim3(256), dim3(512), 0, stream>>>(
        attnbuf, woh, bo, d_out, 4096, 4096, 4096);
}